// Round 1
// baseline (2293.698 us; speedup 1.0000x reference)
//
#include <hip/hip_runtime.h>
#include <cstddef>

#define BB 64
#define SS 256
#define DD 1024
#define MM (BB * SS)  // 16384

__device__ __forceinline__ float silu_f(float v) {
    return v * (1.0f / (1.0f + __expf(-v)));
}

// ---------------------------------------------------------------------------
// NT GEMM: C[M,N] = A[M,K] @ B[N,K]^T  (+ prologue/epilogue variants)
//   SILU_A: apply silu() to A elements while staging to LDS
//   EPI 0: C = acc + bias[c]
//   EPI 1: C = t0*scale[b,c] + shift[b,c] + acc + bias[c]   (adain(t0) + fc)
//   EPI 2: C = resid + silu(acc + bias[c])
// 128x128 tile, BK=16, 256 threads, 8x8 microtile.
// ---------------------------------------------------------------------------
template<bool SILU_A, int EPI>
__global__ __launch_bounds__(256)
void gemm_nt(const float* __restrict__ A, const float* __restrict__ Bw,
             const float* __restrict__ bias,
             const float* __restrict__ t0, const float* __restrict__ scl,
             const float* __restrict__ shf, const float* __restrict__ resid,
             float* __restrict__ C, int M, int N, int K)
{
    __shared__ float As[16][132];
    __shared__ float Bs[16][132];
    const int tid  = threadIdx.x;
    const int row0 = blockIdx.y * 128;
    const int col0 = blockIdx.x * 128;
    const int lr = tid >> 1;          // 0..127: tile row for staging
    const int lk = (tid & 1) * 8;     // 0 or 8: k-offset for staging
    const int ty = tid >> 4;          // 0..15
    const int tx = tid & 15;          // 0..15

    const float* Ag = A  + (size_t)(row0 + lr) * K + lk;
    const float* Bg = Bw + (size_t)(col0 + lr) * K + lk;

    float acc[8][8];
#pragma unroll
    for (int i = 0; i < 8; ++i)
#pragma unroll
        for (int j = 0; j < 8; ++j) acc[i][j] = 0.0f;

    for (int k0 = 0; k0 < K; k0 += 16) {
        float4 a0 = *(const float4*)(Ag + k0);
        float4 a1 = *(const float4*)(Ag + k0 + 4);
        float4 b0 = *(const float4*)(Bg + k0);
        float4 b1 = *(const float4*)(Bg + k0 + 4);
        if (SILU_A) {
            a0.x = silu_f(a0.x); a0.y = silu_f(a0.y); a0.z = silu_f(a0.z); a0.w = silu_f(a0.w);
            a1.x = silu_f(a1.x); a1.y = silu_f(a1.y); a1.z = silu_f(a1.z); a1.w = silu_f(a1.w);
        }
        As[lk+0][lr] = a0.x; As[lk+1][lr] = a0.y; As[lk+2][lr] = a0.z; As[lk+3][lr] = a0.w;
        As[lk+4][lr] = a1.x; As[lk+5][lr] = a1.y; As[lk+6][lr] = a1.z; As[lk+7][lr] = a1.w;
        Bs[lk+0][lr] = b0.x; Bs[lk+1][lr] = b0.y; Bs[lk+2][lr] = b0.z; Bs[lk+3][lr] = b0.w;
        Bs[lk+4][lr] = b1.x; Bs[lk+5][lr] = b1.y; Bs[lk+6][lr] = b1.z; Bs[lk+7][lr] = b1.w;
        __syncthreads();
#pragma unroll
        for (int k = 0; k < 16; ++k) {
            const float4 ra0 = *(const float4*)&As[k][ty * 8];
            const float4 ra1 = *(const float4*)&As[k][ty * 8 + 4];
            const float4 rb0 = *(const float4*)&Bs[k][tx * 8];
            const float4 rb1 = *(const float4*)&Bs[k][tx * 8 + 4];
            const float ra[8] = {ra0.x, ra0.y, ra0.z, ra0.w, ra1.x, ra1.y, ra1.z, ra1.w};
            const float rb[8] = {rb0.x, rb0.y, rb0.z, rb0.w, rb1.x, rb1.y, rb1.z, rb1.w};
#pragma unroll
            for (int i = 0; i < 8; ++i)
#pragma unroll
                for (int j = 0; j < 8; ++j)
                    acc[i][j] = fmaf(ra[i], rb[j], acc[i][j]);
        }
        __syncthreads();
    }

#pragma unroll
    for (int i = 0; i < 8; ++i) {
        const int r = row0 + ty * 8 + i;
        const size_t rowbase = (size_t)r * N;
#pragma unroll
        for (int jj = 0; jj < 8; jj += 4) {
            const int c0 = col0 + tx * 8 + jj;
            float4 o;
            float* ov = (float*)&o;
#pragma unroll
            for (int j = 0; j < 4; ++j) {
                const int c = c0 + j;
                float t = acc[i][jj + j] + bias[c];
                if (EPI == 0) {
                    ov[j] = t;
                } else if (EPI == 1) {
                    const size_t idx = rowbase + c;
                    const int sidx = (r >> 8) * DD + c;  // (batch, channel)
                    ov[j] = fmaf(t0[idx], scl[sidx], shf[sidx]) + t;
                } else {
                    ov[j] = resid[rowbase + c] + silu_f(t);
                }
            }
            *(float4*)&C[rowbase + c0] = o;
        }
    }
}

// ---------------------------------------------------------------------------
// Batched NN GEMM over the seq axis: X[b,t,d] = X[b,t,d] + silu( sum_s W0[t,s]*Y[b,s,d] + b0[t] )
// In-place on X (each element read+written exactly once by its owning thread).
// ---------------------------------------------------------------------------
__global__ __launch_bounds__(256)
void gemm_seq(const float* __restrict__ W0, const float* __restrict__ Y,
              const float* __restrict__ bias0, float* __restrict__ X)
{
    __shared__ float As[16][132];
    __shared__ float Bs[16][132];
    const int tid   = threadIdx.x;
    const int batch = blockIdx.z;
    const int row0  = blockIdx.y * 128;  // t
    const int col0  = blockIdx.x * 128;  // d
    const float* Bg = Y + (size_t)batch * SS * DD;
    float* Cb = X + (size_t)batch * SS * DD;
    const int lrA = tid >> 1;
    const int lkA = (tid & 1) * 8;
    const int kB  = tid >> 4;         // 0..15
    const int nB  = (tid & 15) * 8;   // 0..120
    const int ty = tid >> 4;
    const int tx = tid & 15;

    float acc[8][8];
#pragma unroll
    for (int i = 0; i < 8; ++i)
#pragma unroll
        for (int j = 0; j < 8; ++j) acc[i][j] = 0.0f;

    for (int k0 = 0; k0 < SS; k0 += 16) {
        const float* ap = &W0[(size_t)(row0 + lrA) * SS + k0 + lkA];
        float4 a0 = *(const float4*)(ap);
        float4 a1 = *(const float4*)(ap + 4);
        const float* bp = &Bg[(size_t)(k0 + kB) * DD + col0 + nB];
        float4 b0 = *(const float4*)(bp);
        float4 b1 = *(const float4*)(bp + 4);
        As[lkA+0][lrA] = a0.x; As[lkA+1][lrA] = a0.y; As[lkA+2][lrA] = a0.z; As[lkA+3][lrA] = a0.w;
        As[lkA+4][lrA] = a1.x; As[lkA+5][lrA] = a1.y; As[lkA+6][lrA] = a1.z; As[lkA+7][lrA] = a1.w;
        *(float4*)&Bs[kB][nB]     = b0;
        *(float4*)&Bs[kB][nB + 4] = b1;
        __syncthreads();
#pragma unroll
        for (int k = 0; k < 16; ++k) {
            const float4 ra0 = *(const float4*)&As[k][ty * 8];
            const float4 ra1 = *(const float4*)&As[k][ty * 8 + 4];
            const float4 rb0 = *(const float4*)&Bs[k][tx * 8];
            const float4 rb1 = *(const float4*)&Bs[k][tx * 8 + 4];
            const float ra[8] = {ra0.x, ra0.y, ra0.z, ra0.w, ra1.x, ra1.y, ra1.z, ra1.w};
            const float rb[8] = {rb0.x, rb0.y, rb0.z, rb0.w, rb1.x, rb1.y, rb1.z, rb1.w};
#pragma unroll
            for (int i = 0; i < 8; ++i)
#pragma unroll
                for (int j = 0; j < 8; ++j)
                    acc[i][j] = fmaf(ra[i], rb[j], acc[i][j]);
        }
        __syncthreads();
    }

#pragma unroll
    for (int i = 0; i < 8; ++i) {
        const int r = row0 + ty * 8 + i;       // t within batch
        const float bt = bias0[r];
        const size_t rowbase = (size_t)r * DD;
#pragma unroll
        for (int jj = 0; jj < 8; jj += 4) {
            const int c0 = col0 + tx * 8 + jj;
            float4 res = *(const float4*)&Cb[rowbase + c0];
            float4 o;
            o.x = res.x + silu_f(acc[i][jj + 0] + bt);
            o.y = res.y + silu_f(acc[i][jj + 1] + bt);
            o.z = res.z + silu_f(acc[i][jj + 2] + bt);
            o.w = res.w + silu_f(acc[i][jj + 3] + bt);
            *(float4*)&Cb[rowbase + c0] = o;
        }
    }
}

// ---------------------------------------------------------------------------
// AdaIN stats: per (b,d) channel over s: scale = s_std/c_std, shift = s_mean - c_mean*scale
// var with ddof=1 (torch .var() unbiased), eps inside sqrt.
// ---------------------------------------------------------------------------
__global__ __launch_bounds__(256)
void adain_stats(const float* __restrict__ t0, const float* __restrict__ style,
                 float* __restrict__ scl, float* __restrict__ shf)
{
    const int idx = blockIdx.x * 256 + threadIdx.x;  // 0..65535
    const int b = idx >> 10;
    const int d = idx & (DD - 1);
    const float* pc = t0    + (size_t)b * SS * DD + d;
    const float* ps = style + (size_t)b * SS * DD + d;
    float sc = 0.f, sc2 = 0.f, ss = 0.f, ss2 = 0.f;
    for (int s = 0; s < SS; ++s) {
        const float c  = pc[(size_t)s * DD];
        const float st = ps[(size_t)s * DD];
        sc += c;  sc2 = fmaf(c, c, sc2);
        ss += st; ss2 = fmaf(st, st, ss2);
    }
    const float mc = sc * (1.0f / SS);
    const float ms = ss * (1.0f / SS);
    float vc = (sc2 - (float)SS * mc * mc) * (1.0f / (SS - 1));
    float vs = (ss2 - (float)SS * ms * ms) * (1.0f / (SS - 1));
    vc = fmaxf(vc, 0.f);
    vs = fmaxf(vs, 0.f);
    const float csd = sqrtf(vc + 1e-5f);
    const float ssd = sqrtf(vs + 1e-5f);
    const float sca = ssd / csd;
    scl[idx] = sca;
    shf[idx] = ms - mc * sca;
}

// ---------------------------------------------------------------------------
// LayerNorm over last dim (D=1024): one wave per row.
// ---------------------------------------------------------------------------
__global__ __launch_bounds__(256)
void ln_rows(const float* __restrict__ X, const float* __restrict__ g,
             const float* __restrict__ beta, float* __restrict__ Y)
{
    const int row  = blockIdx.x * 4 + (threadIdx.x >> 6);
    const int lane = threadIdx.x & 63;
    const float* xr = X + (size_t)row * DD;
    float4 v[4];
    float sum = 0.f, sq = 0.f;
#pragma unroll
    for (int c = 0; c < 4; ++c) {
        v[c] = *(const float4*)&xr[c * 256 + lane * 4];
        sum += v[c].x + v[c].y + v[c].z + v[c].w;
        sq  += v[c].x * v[c].x + v[c].y * v[c].y + v[c].z * v[c].z + v[c].w * v[c].w;
    }
#pragma unroll
    for (int off = 32; off > 0; off >>= 1) {
        sum += __shfl_down(sum, off, 64);
        sq  += __shfl_down(sq,  off, 64);
    }
    sum = __shfl(sum, 0, 64);
    sq  = __shfl(sq,  0, 64);
    const float mu = sum * (1.0f / DD);
    float var = sq * (1.0f / DD) - mu * mu;
    var = fmaxf(var, 0.f);
    const float rs = rsqrtf(var + 1e-5f);
    float* yr = Y + (size_t)row * DD;
#pragma unroll
    for (int c = 0; c < 4; ++c) {
        const int col = c * 256 + lane * 4;
        const float4 gv = *(const float4*)&g[col];
        const float4 bv = *(const float4*)&beta[col];
        float4 o;
        o.x = (v[c].x - mu) * rs * gv.x + bv.x;
        o.y = (v[c].y - mu) * rs * gv.y + bv.y;
        o.z = (v[c].z - mu) * rs * gv.z + bv.z;
        o.w = (v[c].w - mu) * rs * gv.w + bv.w;
        *(float4*)&yr[col] = o;
    }
}

// ---------------------------------------------------------------------------
// Copy embed/style passthrough outputs (float4, grid-stride).
// ---------------------------------------------------------------------------
__global__ __launch_bounds__(256)
void copy_pass(const float4* __restrict__ emb, const float4* __restrict__ sty,
               float4* __restrict__ out_emb, float4* __restrict__ out_sty)
{
    const int n4 = MM * DD / 4;  // 4194304
    const int stride = gridDim.x * blockDim.x;
    for (int i = blockIdx.x * blockDim.x + threadIdx.x; i < n4; i += stride) {
        out_emb[i] = emb[i];
        out_sty[i] = sty[i];
    }
}

extern "C" void kernel_launch(void* const* d_in, const int* in_sizes, int n_in,
                              void* d_out, int out_size, void* d_ws, size_t ws_size,
                              hipStream_t stream)
{
    const float* x     = (const float*)d_in[0];
    const float* embed = (const float*)d_in[1];
    const float* style = (const float*)d_in[2];
    const float* Wc    = (const float*)d_in[3];
    const float* bc    = (const float*)d_in[4];
    const float* We    = (const float*)d_in[5];
    const float* be    = (const float*)d_in[6];
    const float* W0    = (const float*)d_in[7];
    const float* b0    = (const float*)d_in[8];
    const float* W1    = (const float*)d_in[9];
    const float* b1    = (const float*)d_in[10];
    const float* g0    = (const float*)d_in[11];
    const float* beta0 = (const float*)d_in[12];
    const float* g1    = (const float*)d_in[13];
    const float* beta1 = (const float*)d_in[14];

    float* out     = (float*)d_out;
    float* out_x   = out;                    // final x
    float* out_emb = out + (size_t)MM * DD;  // embed passthrough (scratch buf1 until end)
    float* out_sty = out + (size_t)2 * MM * DD;  // style passthrough (scratch buf0 until end)

    float* buf0 = out_sty;  // t0 -> y -> z
    float* buf1 = out_emb;  // x1 -> x2 (in place)
    float* scl = (float*)d_ws;          // [B*D]
    float* shf = scl + BB * DD;         // [B*D]

    const dim3 gNT(DD / 128, MM / 128);  // (8, 128)

    // 1) t0 = x @ Wc^T + bc
    gemm_nt<false, 0><<<gNT, 256, 0, stream>>>(x, Wc, bc, nullptr, nullptr, nullptr,
                                               nullptr, buf0, MM, DD, 2 * DD);
    // 2) AdaIN stats of (t0, style) -> scale/shift per (b,d)
    adain_stats<<<BB * DD / 256, 256, 0, stream>>>(buf0, style, scl, shf);
    // 3) x1 = adain(t0) + silu(embed) @ We^T + be
    gemm_nt<true, 1><<<gNT, 256, 0, stream>>>(embed, We, be, buf0, scl, shf,
                                              nullptr, buf1, MM, DD, DD);
    // 4) y = LN(x1; g0, beta0)
    ln_rows<<<MM / 4, 256, 0, stream>>>(buf1, g0, beta0, buf0);
    // 5) x2 = x1 + silu(W0 @ y + b0)   (in-place on buf1)
    gemm_seq<<<dim3(DD / 128, SS / 128, BB), 256, 0, stream>>>(W0, buf0, b0, buf1);
    // 6) z = LN(x2; g1, beta1)
    ln_rows<<<MM / 4, 256, 0, stream>>>(buf1, g1, beta1, buf0);
    // 7) out_x = x2 + silu(z @ W1^T + b1)
    gemm_nt<false, 2><<<gNT, 256, 0, stream>>>(buf0, W1, b1, nullptr, nullptr, nullptr,
                                               buf1, out_x, MM, DD, DD);
    // 8) passthrough outputs (overwrites the scratch regions last)
    copy_pass<<<4096, 256, 0, stream>>>((const float4*)embed, (const float4*)style,
                                        (float4*)out_emb, (float4*)out_sty);
}